// Round 2
// baseline (10658.171 us; speedup 1.0000x reference)
//
#include <hip/hip_runtime.h>

// PointerNetwork: B=64, N=512, E=512, 2E=1024, T=64 decode steps.
// Round 2: single persistent cooperative kernel for the 64-step loop
// (3 grid barriers/step instead of 3 kernel launches/step), plus
// bank-conflict-free kenc register tiling (4+4 column split).
// All f32 (argmax chain is precision-critical). Indices written as float.

#define DEV __device__ __forceinline__

DEV float sigm(float x) { return __fdividef(1.0f, 1.0f + __expf(-x)); }
DEV float tanh_fast(float x) {
  float e = __expf(2.0f * x);                 // tanh = 1 - 2/(e^2x+1)
  return 1.0f - __fdividef(2.0f, e + 1.0f);   // inf-safe at both ends
}

#define FMA4(acc, xv, wv)                                                      \
  acc = fmaf((xv).x, (wv).x, acc); acc = fmaf((xv).y, (wv).y, acc);            \
  acc = fmaf((xv).z, (wv).z, acc); acc = fmaf((xv).w, (wv).w, acc)

// ---------------- enc GEMM: C[32768x512] = A[32768x1024] @ B[512x1024]^T + bias
// Register tile: thread (tx,ty) owns rows {ty*4+i, 64+ty*4+i} x cols
// {tx*4+j, 64+tx*4+j}. LDS reads are float4 at 16B lane stride -> 2 lanes/bank
// (free), a_s reads broadcast within ty-groups.
__global__ __launch_bounds__(256) void kenc(const float* __restrict__ A,
                                            const float* __restrict__ Bm,
                                            const float* __restrict__ bias,
                                            float* __restrict__ C) {
  __shared__ float a_s[16][132];
  __shared__ float b_s[16][132];
  const int t = threadIdx.x;
  const int row = t >> 1;            // 0..127
  const int kq = (t & 1) * 8;        // 0 or 8
  const float* Arow = A + (blockIdx.x * 128 + row) * 1024 + kq;
  const float* Brow = Bm + (blockIdx.y * 128 + row) * 1024 + kq;
  const int tx = t & 15, ty = t >> 4;
  float acc[8][8] = {};
  for (int k0 = 0; k0 < 1024; k0 += 16) {
    float4 av0 = *(const float4*)(Arow + k0);
    float4 av1 = *(const float4*)(Arow + k0 + 4);
    float4 bv0 = *(const float4*)(Brow + k0);
    float4 bv1 = *(const float4*)(Brow + k0 + 4);
    __syncthreads();
    a_s[kq+0][row]=av0.x; a_s[kq+1][row]=av0.y; a_s[kq+2][row]=av0.z; a_s[kq+3][row]=av0.w;
    a_s[kq+4][row]=av1.x; a_s[kq+5][row]=av1.y; a_s[kq+6][row]=av1.z; a_s[kq+7][row]=av1.w;
    b_s[kq+0][row]=bv0.x; b_s[kq+1][row]=bv0.y; b_s[kq+2][row]=bv0.z; b_s[kq+3][row]=bv0.w;
    b_s[kq+4][row]=bv1.x; b_s[kq+5][row]=bv1.y; b_s[kq+6][row]=bv1.z; b_s[kq+7][row]=bv1.w;
    __syncthreads();
    #pragma unroll
    for (int k = 0; k < 16; ++k) {
      float a[8], b[8];
      *(float4*)(a)   = *(const float4*)&a_s[k][ty*4];
      *(float4*)(a+4) = *(const float4*)&a_s[k][64 + ty*4];
      *(float4*)(b)   = *(const float4*)&b_s[k][tx*4];
      *(float4*)(b+4) = *(const float4*)&b_s[k][64 + tx*4];
      #pragma unroll
      for (int i = 0; i < 8; ++i)
        #pragma unroll
        for (int j = 0; j < 8; ++j)
          acc[i][j] = fmaf(a[i], b[j], acc[i][j]);
    }
  }
  const int mb = blockIdx.x * 128;
  const int eb = blockIdx.y * 128;
  float4 bv0 = *(const float4*)&bias[eb + tx*4];
  float4 bv1 = *(const float4*)&bias[eb + 64 + tx*4];
  #pragma unroll
  for (int i = 0; i < 8; ++i) {
    const int r = mb + ((i < 4) ? (ty*4 + i) : (64 + ty*4 + (i - 4)));
    float* orow = C + r * 512 + eb;
    float4 o0, o1;
    o0.x=acc[i][0]+bv0.x; o0.y=acc[i][1]+bv0.y; o0.z=acc[i][2]+bv0.z; o0.w=acc[i][3]+bv0.w;
    o1.x=acc[i][4]+bv1.x; o1.y=acc[i][5]+bv1.y; o1.z=acc[i][6]+bv1.z; o1.w=acc[i][7]+bv1.w;
    *(float4*)(orow + tx*4) = o0;
    *(float4*)(orow + 64 + tx*4) = o1;
  }
}

// ---------------- grid barrier (generation counter). bar[0]=count, bar[16]=gen.
DEV void gbar(unsigned* bar) {
  __syncthreads();
  if (threadIdx.x == 0) {
    unsigned g0 = __hip_atomic_load(bar + 16, __ATOMIC_RELAXED, __HIP_MEMORY_SCOPE_AGENT);
    __threadfence();
    unsigned a = __hip_atomic_fetch_add(bar, 1u, __ATOMIC_ACQ_REL, __HIP_MEMORY_SCOPE_AGENT);
    if (a == 255u) {                           // last arriver of 256 blocks
      __hip_atomic_store(bar, 0u, __ATOMIC_RELAXED, __HIP_MEMORY_SCOPE_AGENT);
      __hip_atomic_fetch_add(bar + 16, 1u, __ATOMIC_RELEASE, __HIP_MEMORY_SCOPE_AGENT);
    } else {
      while (__hip_atomic_load(bar + 16, __ATOMIC_ACQUIRE, __HIP_MEMORY_SCOPE_AGENT) == g0)
        __builtin_amdgcn_s_sleep(2);
    }
    __threadfence();
  }
  __syncthreads();
}

// ---------------- persistent 64-step decode loop. 256 blocks x 256 threads.
// Per step: phaseA (argmax/logp of prev + gather + gates -> hx) | gbar |
//           phaseQ (g<128: q = hx@Wd^T+bd)                      | gbar |
//           phaseS (scores, 128 n per block)                    | gbar |
__global__ __launch_bounds__(256) void kloop(
    const float* __restrict__ TE, const float* __restrict__ encd,
    const float* __restrict__ W_ih, const float* __restrict__ b_ih,
    const float* __restrict__ b_hh, const float* __restrict__ Wd,
    const float* __restrict__ bd, const float* __restrict__ wr,
    const float* __restrict__ br, const float* __restrict__ enc,
    float* __restrict__ scores, float* __restrict__ hx, float* __restrict__ q,
    unsigned* __restrict__ bar, float* __restrict__ out_logp,
    float* __restrict__ out_idx) {
  __shared__ int   idx_s[64];
  __shared__ float mx_s[64];
  __shared__ float wsum_s[4];
  __shared__ float part_s[4][64][6];
  __shared__ float partq_s[4][64][4];
  const int g = blockIdx.x;
  const int t = threadIdx.x;
  const int lane = t & 63;
  const int wu = __builtin_amdgcn_readfirstlane(t >> 6);

  // hoisted for scores phase
  const int sb = g >> 2, sc = g & 3;       // batch, n-quarter
  const int le = lane & 15, nl = lane >> 4;
  float4 wv[8];
  #pragma unroll
  for (int j = 0; j < 8; ++j) wv[j] = *(const float4*)(wr + le * 4 + 64 * j);
  const float brv = br[0];

  for (int step = 0; step <= 64; ++step) {
    // ---- phase A1: argmax of previous step's scores (redundant per block)
    if (step > 0) {
      const int row = t >> 2, qq = t & 3;
      const float* srow = scores + row * 512;
      float bv = -3.0e38f; int bi = 0;
      #pragma unroll 8
      for (int n = qq; n < 512; n += 4) {
        float s = srow[n];
        if (s > bv) { bv = s; bi = n; }     // strict > keeps first occurrence
      }
      #pragma unroll
      for (int m = 1; m <= 2; m <<= 1) {    // combine the 4 stride-classes
        float ov = __shfl_xor(bv, m);
        int   oi = __shfl_xor(bi, m);
        if (ov > bv || (ov == bv && oi < bi)) { bv = ov; bi = oi; }
      }
      if (qq == 0) { idx_s[row] = bi; mx_s[row] = bv; }
    }
    __syncthreads();

    // ---- phase A2: blocks 0..63 write logp row + idx for step-1
    if (step > 0 && g < 64) {
      const float* srow = scores + g * 512;
      const float mx = mx_s[g];
      float ssum = __expf(srow[t] - mx) + __expf(srow[t + 256] - mx);
      #pragma unroll
      for (int m = 1; m <= 32; m <<= 1) ssum += __shfl_xor(ssum, m);
      if (lane == 0) wsum_s[wu] = ssum;
    }
    __syncthreads();
    if (step > 0 && g < 64) {
      const float* srow = scores + g * 512;
      const float lse = mx_s[g] + __logf(wsum_s[0] + wsum_s[1] + wsum_s[2] + wsum_s[3]);
      float* orow = out_logp + (g * 64 + (step - 1)) * 512;
      orow[t]       = srow[t]       - lse;
      orow[t + 256] = srow[t + 256] - lse;
      if (t == 0) out_idx[g * 64 + (step - 1)] = (float)idx_s[g];
    }
    if (step == 64) break;

    // ---- phase A3: gates GEMM slice (i,g,o gates; f-gate dead: c_prev=0)
    {
      const int k0 = 2 * g, k1 = 2 * g + 1;
      const int dbase = wu * 256;
      const float* p0 = W_ih + (k0        ) * 1024 + dbase;
      const float* p1 = W_ih + (k1        ) * 1024 + dbase;
      const float* p2 = W_ih + (1024 + k0) * 1024 + dbase;
      const float* p3 = W_ih + (1024 + k1) * 1024 + dbase;
      const float* p4 = W_ih + (1536 + k0) * 1024 + dbase;
      const float* p5 = W_ih + (1536 + k1) * 1024 + dbase;
      const float* xr = (step == 0) ? (encd + lane * 1024 + dbase)
                                    : (TE + (lane * 512 + idx_s[lane]) * 1024 + dbase);
      float a0=0, a1=0, a2=0, a3=0, a4=0, a5=0;
      #pragma unroll 4
      for (int d = 0; d < 256; d += 4) {
        float4 xv = *(const float4*)(xr + d);
        float4 v0 = *(const float4*)(p0 + d);
        float4 v1 = *(const float4*)(p1 + d);
        float4 v2 = *(const float4*)(p2 + d);
        float4 v3 = *(const float4*)(p3 + d);
        float4 v4 = *(const float4*)(p4 + d);
        float4 v5 = *(const float4*)(p5 + d);
        FMA4(a0, xv, v0); FMA4(a1, xv, v1); FMA4(a2, xv, v2);
        FMA4(a3, xv, v3); FMA4(a4, xv, v4); FMA4(a5, xv, v5);
      }
      part_s[wu][lane][0]=a0; part_s[wu][lane][1]=a1; part_s[wu][lane][2]=a2;
      part_s[wu][lane][3]=a3; part_s[wu][lane][4]=a4; part_s[wu][lane][5]=a5;
      __syncthreads();
      if (t < 64) {
        float s0=0, s1=0, s2=0, s3=0, s4=0, s5=0;
        #pragma unroll
        for (int u = 0; u < 4; ++u) {
          s0 += part_s[u][t][0]; s1 += part_s[u][t][1]; s2 += part_s[u][t][2];
          s3 += part_s[u][t][3]; s4 += part_s[u][t][4]; s5 += part_s[u][t][5];
        }
        const float gi0 = s0 + b_ih[k0] + b_hh[k0];
        const float gi1 = s1 + b_ih[k1] + b_hh[k1];
        const float gg0 = s2 + b_ih[1024 + k0] + b_hh[1024 + k0];
        const float gg1 = s3 + b_ih[1024 + k1] + b_hh[1024 + k1];
        const float go0 = s4 + b_ih[1536 + k0] + b_hh[1536 + k0];
        const float go1 = s5 + b_ih[1536 + k1] + b_hh[1536 + k1];
        const float c0 = sigm(gi0) * tanh_fast(gg0);
        const float c1 = sigm(gi1) * tanh_fast(gg1);
        hx[t * 512 + k0] = sigm(go0) * tanh_fast(c0);
        hx[t * 512 + k1] = sigm(go1) * tanh_fast(c1);
      }
    }
    gbar(bar);

    // ---- phase Q: q = hx @ Wd^T + bd (blocks 0..127, 4 e-cols each)
    if (g < 128) {
      const int dbase = wu * 128;
      const int e0 = g * 4;
      const float* w0 = Wd + (e0 + 0) * 512 + dbase;
      const float* w1 = Wd + (e0 + 1) * 512 + dbase;
      const float* w2 = Wd + (e0 + 2) * 512 + dbase;
      const float* w3 = Wd + (e0 + 3) * 512 + dbase;
      const float* xr = hx + lane * 512 + dbase;
      float a0=0, a1=0, a2=0, a3=0;
      #pragma unroll 8
      for (int d = 0; d < 128; d += 4) {
        float4 xv = *(const float4*)(xr + d);
        float4 v0 = *(const float4*)(w0 + d);
        float4 v1 = *(const float4*)(w1 + d);
        float4 v2 = *(const float4*)(w2 + d);
        float4 v3 = *(const float4*)(w3 + d);
        FMA4(a0, xv, v0); FMA4(a1, xv, v1); FMA4(a2, xv, v2); FMA4(a3, xv, v3);
      }
      partq_s[wu][lane][0]=a0; partq_s[wu][lane][1]=a1;
      partq_s[wu][lane][2]=a2; partq_s[wu][lane][3]=a3;
      __syncthreads();
      if (t < 64) {
        float4 r;
        r.x = partq_s[0][t][0]+partq_s[1][t][0]+partq_s[2][t][0]+partq_s[3][t][0] + bd[e0+0];
        r.y = partq_s[0][t][1]+partq_s[1][t][1]+partq_s[2][t][1]+partq_s[3][t][1] + bd[e0+1];
        r.z = partq_s[0][t][2]+partq_s[1][t][2]+partq_s[2][t][2]+partq_s[3][t][2] + bd[e0+2];
        r.w = partq_s[0][t][3]+partq_s[1][t][3]+partq_s[2][t][3]+partq_s[3][t][3] + bd[e0+3];
        *(float4*)(q + t * 512 + e0) = r;
      }
    }
    gbar(bar);

    // ---- phase S: scores[b,n] = sum_e wr[e]*tanh(q[b,e]+enc[b,n,e]) + br
    {
      float4 qv[8];
      const float* qrow = q + sb * 512 + le * 4;
      #pragma unroll
      for (int j = 0; j < 8; ++j) qv[j] = *(const float4*)(qrow + 64 * j);
      #pragma unroll
      for (int i = 0; i < 8; ++i) {
        const int n = sc * 128 + wu * 32 + i * 4 + nl;
        const float* erow = enc + (sb * 512 + n) * 512 + le * 4;
        float acc = 0.0f;
        #pragma unroll
        for (int j = 0; j < 8; ++j) {
          float4 ev = *(const float4*)(erow + 64 * j);
          acc += wv[j].x * tanh_fast(qv[j].x + ev.x);
          acc += wv[j].y * tanh_fast(qv[j].y + ev.y);
          acc += wv[j].z * tanh_fast(qv[j].z + ev.z);
          acc += wv[j].w * tanh_fast(qv[j].w + ev.w);
        }
        acc += __shfl_xor(acc, 1);
        acc += __shfl_xor(acc, 2);
        acc += __shfl_xor(acc, 4);
        acc += __shfl_xor(acc, 8);
        if (le == 0) scores[sb * 512 + n] = acc + brv;
      }
    }
    gbar(bar);
  }
}

extern "C" void kernel_launch(void* const* d_in, const int* in_sizes, int n_in,
                              void* d_out, int out_size, void* d_ws, size_t ws_size,
                              hipStream_t stream) {
  const float* TE   = (const float*)d_in[0];   // [64,512,1024]
  const float* encd = (const float*)d_in[1];   // [64,1024]
  const float* W_ih = (const float*)d_in[2];   // [2048,1024]
  const float* b_ih = (const float*)d_in[3];   // [2048]
  const float* b_hh = (const float*)d_in[4];   // [2048]
  const float* Wd   = (const float*)d_in[5];   // [512,512]
  const float* bd   = (const float*)d_in[6];   // [512]
  const float* We   = (const float*)d_in[7];   // [512,1024]
  const float* be   = (const float*)d_in[8];   // [512]
  const float* wr   = (const float*)d_in[9];   // [512]
  const float* br   = (const float*)d_in[10];  // [1]

  float* out     = (float*)d_out;              // logp [64][64][512]
  float* out_idx = out + 64 * 64 * 512;        // indices as float [64][64]

  float* enc     = (float*)d_ws;               // 16,777,216 f (64 MB)
  float* scores  = enc + 16777216;             // 32,768 f
  float* hx      = scores + 32768;             // 32,768 f
  float* q       = hx + 32768;                 // 32,768 f
  unsigned* bar  = (unsigned*)(q + 32768);     // 2 words used (count, gen)

  hipMemsetAsync(bar, 0, 256, stream);
  kenc<<<dim3(256, 4), 256, 0, stream>>>(TE, We, be, enc);

  void* args[] = {(void*)&TE, (void*)&encd, (void*)&W_ih, (void*)&b_ih,
                  (void*)&b_hh, (void*)&Wd, (void*)&bd, (void*)&wr,
                  (void*)&br, (void*)&enc, (void*)&scores, (void*)&hx,
                  (void*)&q, (void*)&bar, (void*)&out, (void*)&out_idx};
  hipLaunchCooperativeKernel((void*)kloop, dim3(256), dim3(256), args, 0, stream);
}

// Round 3
// 3111.037 us; speedup vs baseline: 3.4259x; 3.4259x over previous
//
#include <hip/hip_runtime.h>

// PointerNetwork: B=64, N=512, E=512, 2E=1024, T=64 decode steps.
// Round 3: back to multi-launch (coop barrier flushed L2 -> 3x regression).
//   kenc (once): enc = TE@We^T + be, conflict-free 4+4 register tiling
//   per step t: kstep (argmax-from-mbuf + logp + gather + gates -> hx)
//               kq    (q = hx@Wd^T + bd, 256 blocks)
//               kscore(scores + per-row packed atomicMax -> mbuf, 1024 blocks)
//   kfin (once): softmax/argmax for step 63.
// All f32 (argmax chain is precision-critical). Indices written as float.

#define DEV __device__ __forceinline__

DEV float sigm(float x) { return __fdividef(1.0f, 1.0f + __expf(-x)); }
DEV float tanh_fast(float x) {
  float e = __expf(2.0f * x);                 // tanh = 1 - 2/(e^2x+1)
  return 1.0f - __fdividef(2.0f, e + 1.0f);   // inf-safe at both ends
}

// monotone f32 -> u32 key (order-preserving), packed with (511-n) so that
// u64 atomicMax = (max score, ties -> smallest n)  == jnp.argmax semantics.
DEV unsigned long long pack_score(float s, int n) {
  unsigned u = __float_as_uint(s);
  unsigned key = (u & 0x80000000u) ? ~u : (u | 0x80000000u);
  return ((unsigned long long)key << 32) | (unsigned)(511 - n);
}
DEV float unpack_score(unsigned long long p) {
  unsigned key = (unsigned)(p >> 32);
  unsigned u = (key & 0x80000000u) ? (key & 0x7fffffffu) : ~key;
  return __uint_as_float(u);
}
DEV int unpack_idx(unsigned long long p) { return 511 - (int)(p & 0xffffu); }

#define FMA4(acc, xv, wv)                                                      \
  acc = fmaf((xv).x, (wv).x, acc); acc = fmaf((xv).y, (wv).y, acc);            \
  acc = fmaf((xv).z, (wv).z, acc); acc = fmaf((xv).w, (wv).w, acc)

// ---------------- enc GEMM: C[32768x512] = A[32768x1024] @ B[512x1024]^T + bias
// Thread (tx,ty) owns rows {ty*4+i, 64+ty*4+i} x cols {tx*4+j, 64+tx*4+j}.
// LDS reads: float4 at 16B stride -> 2 lanes/bank (free); a_s broadcasts.
__global__ __launch_bounds__(256) void kenc(const float* __restrict__ A,
                                            const float* __restrict__ Bm,
                                            const float* __restrict__ bias,
                                            float* __restrict__ C) {
  __shared__ float a_s[16][132];
  __shared__ float b_s[16][132];
  const int t = threadIdx.x;
  const int row = t >> 1;            // 0..127
  const int kq = (t & 1) * 8;        // 0 or 8
  const float* Arow = A + (blockIdx.x * 128 + row) * 1024 + kq;
  const float* Brow = Bm + (blockIdx.y * 128 + row) * 1024 + kq;
  const int tx = t & 15, ty = t >> 4;
  float acc[8][8] = {};
  for (int k0 = 0; k0 < 1024; k0 += 16) {
    float4 av0 = *(const float4*)(Arow + k0);
    float4 av1 = *(const float4*)(Arow + k0 + 4);
    float4 bv0 = *(const float4*)(Brow + k0);
    float4 bv1 = *(const float4*)(Brow + k0 + 4);
    __syncthreads();
    a_s[kq+0][row]=av0.x; a_s[kq+1][row]=av0.y; a_s[kq+2][row]=av0.z; a_s[kq+3][row]=av0.w;
    a_s[kq+4][row]=av1.x; a_s[kq+5][row]=av1.y; a_s[kq+6][row]=av1.z; a_s[kq+7][row]=av1.w;
    b_s[kq+0][row]=bv0.x; b_s[kq+1][row]=bv0.y; b_s[kq+2][row]=bv0.z; b_s[kq+3][row]=bv0.w;
    b_s[kq+4][row]=bv1.x; b_s[kq+5][row]=bv1.y; b_s[kq+6][row]=bv1.z; b_s[kq+7][row]=bv1.w;
    __syncthreads();
    #pragma unroll
    for (int k = 0; k < 16; ++k) {
      float a[8], b[8];
      *(float4*)(a)   = *(const float4*)&a_s[k][ty*4];
      *(float4*)(a+4) = *(const float4*)&a_s[k][64 + ty*4];
      *(float4*)(b)   = *(const float4*)&b_s[k][tx*4];
      *(float4*)(b+4) = *(const float4*)&b_s[k][64 + tx*4];
      #pragma unroll
      for (int i = 0; i < 8; ++i)
        #pragma unroll
        for (int j = 0; j < 8; ++j)
          acc[i][j] = fmaf(a[i], b[j], acc[i][j]);
    }
  }
  const int mb = blockIdx.x * 128;
  const int eb = blockIdx.y * 128;
  float4 bv0 = *(const float4*)&bias[eb + tx*4];
  float4 bv1 = *(const float4*)&bias[eb + 64 + tx*4];
  #pragma unroll
  for (int i = 0; i < 8; ++i) {
    const int r = mb + ((i < 4) ? (ty*4 + i) : (64 + ty*4 + (i - 4)));
    float* orow = C + r * 512 + eb;
    float4 o0, o1;
    o0.x=acc[i][0]+bv0.x; o0.y=acc[i][1]+bv0.y; o0.z=acc[i][2]+bv0.z; o0.w=acc[i][3]+bv0.w;
    o1.x=acc[i][4]+bv1.x; o1.y=acc[i][5]+bv1.y; o1.z=acc[i][6]+bv1.z; o1.w=acc[i][7]+bv1.w;
    *(float4*)(orow + tx*4) = o0;
    *(float4*)(orow + 64 + tx*4) = o1;
  }
}

// ---------------- per-step kernel 1: logp/idx of step-1 + gather + gates -> hx
// 256 blocks x 256 thr. Block g owns hx columns k0=2g, k1=2g+1.
__global__ __launch_bounds__(256) void kstep(
    const float* __restrict__ TE, const float* __restrict__ encd,
    const float* __restrict__ W_ih, const float* __restrict__ b_ih,
    const float* __restrict__ b_hh, const float* __restrict__ scores,
    const unsigned long long* __restrict__ mprev,
    unsigned long long* __restrict__ mcur,
    float* __restrict__ hx, float* __restrict__ out_logp,
    float* __restrict__ out_idx, int step) {
  __shared__ int   idx_s[64];
  __shared__ float mx_s[64];
  __shared__ float wsum_s[4];
  __shared__ float part_s[4][64][6];
  const int g = blockIdx.x;
  const int t = threadIdx.x;
  const int lane = t & 63;
  const int wu = __builtin_amdgcn_readfirstlane(t >> 6);

  // reset the mbuf kscore(step) will write (block 0 only; kernel-boundary orders)
  if (g == 0 && t < 64) mcur[t] = 0ULL;

  // A1: previous step's argmax/max from packed atomics
  if (step > 0 && t < 64) {
    unsigned long long p = mprev[t];
    idx_s[t] = unpack_idx(p);
    mx_s[t]  = unpack_score(p);
  }
  __syncthreads();

  // A2: blocks 0..63 compute lse + write logp row + idx for step-1
  if (step > 0 && g < 64) {
    const float* srow = scores + g * 512;
    const float mx = mx_s[g];
    float ssum = __expf(srow[t] - mx) + __expf(srow[t + 256] - mx);
    #pragma unroll
    for (int m = 1; m <= 32; m <<= 1) ssum += __shfl_xor(ssum, m);
    if (lane == 0) wsum_s[wu] = ssum;
  }
  __syncthreads();
  if (step > 0 && g < 64) {
    const float* srow = scores + g * 512;
    const float lse = mx_s[g] + __logf(wsum_s[0] + wsum_s[1] + wsum_s[2] + wsum_s[3]);
    float* orow = out_logp + (g * 64 + (step - 1)) * 512;
    orow[t]       = srow[t]       - lse;
    orow[t + 256] = srow[t + 256] - lse;
    if (t == 0) out_idx[g * 64 + (step - 1)] = (float)idx_s[g];
  }

  // A3: gates GEMM slice (i,g,o gates; f-gate dead: c_prev=0)
  const int k0 = 2 * g, k1 = 2 * g + 1;
  const int dbase = wu * 256;
  const float* p0 = W_ih + (k0        ) * 1024 + dbase;
  const float* p1 = W_ih + (k1        ) * 1024 + dbase;
  const float* p2 = W_ih + (1024 + k0) * 1024 + dbase;
  const float* p3 = W_ih + (1024 + k1) * 1024 + dbase;
  const float* p4 = W_ih + (1536 + k0) * 1024 + dbase;
  const float* p5 = W_ih + (1536 + k1) * 1024 + dbase;
  const float* xr = (step == 0) ? (encd + lane * 1024 + dbase)
                                : (TE + (lane * 512 + idx_s[lane]) * 1024 + dbase);
  float a0=0, a1=0, a2=0, a3=0, a4=0, a5=0;
  #pragma unroll 4
  for (int d = 0; d < 256; d += 4) {
    float4 xv = *(const float4*)(xr + d);
    float4 v0 = *(const float4*)(p0 + d);
    float4 v1 = *(const float4*)(p1 + d);
    float4 v2 = *(const float4*)(p2 + d);
    float4 v3 = *(const float4*)(p3 + d);
    float4 v4 = *(const float4*)(p4 + d);
    float4 v5 = *(const float4*)(p5 + d);
    FMA4(a0, xv, v0); FMA4(a1, xv, v1); FMA4(a2, xv, v2);
    FMA4(a3, xv, v3); FMA4(a4, xv, v4); FMA4(a5, xv, v5);
  }
  part_s[wu][lane][0]=a0; part_s[wu][lane][1]=a1; part_s[wu][lane][2]=a2;
  part_s[wu][lane][3]=a3; part_s[wu][lane][4]=a4; part_s[wu][lane][5]=a5;
  __syncthreads();

  if (t < 64) {
    float s0=0, s1=0, s2=0, s3=0, s4=0, s5=0;
    #pragma unroll
    for (int u = 0; u < 4; ++u) {
      s0 += part_s[u][t][0]; s1 += part_s[u][t][1]; s2 += part_s[u][t][2];
      s3 += part_s[u][t][3]; s4 += part_s[u][t][4]; s5 += part_s[u][t][5];
    }
    const float gi0 = s0 + b_ih[k0] + b_hh[k0];
    const float gi1 = s1 + b_ih[k1] + b_hh[k1];
    const float gg0 = s2 + b_ih[1024 + k0] + b_hh[1024 + k0];
    const float gg1 = s3 + b_ih[1024 + k1] + b_hh[1024 + k1];
    const float go0 = s4 + b_ih[1536 + k0] + b_hh[1536 + k0];
    const float go1 = s5 + b_ih[1536 + k1] + b_hh[1536 + k1];
    const float c0 = sigm(gi0) * tanh_fast(gg0);
    const float c1 = sigm(gi1) * tanh_fast(gg1);
    hx[t * 512 + k0] = sigm(go0) * tanh_fast(c0);
    hx[t * 512 + k1] = sigm(go1) * tanh_fast(c1);
  }
}

// ---------------- q = hx @ Wd^T + bd. 256 blocks; block owns e = 2g, 2g+1.
__global__ __launch_bounds__(256) void kq(const float* __restrict__ hx,
                                          const float* __restrict__ Wd,
                                          const float* __restrict__ bd,
                                          float* __restrict__ q) {
  __shared__ float part_s[4][64][2];
  const int g = blockIdx.x;
  const int t = threadIdx.x, lane = t & 63;
  const int wu = __builtin_amdgcn_readfirstlane(t >> 6);
  const int dbase = wu * 128;
  const int e0 = g * 2;
  const float* w0 = Wd + (e0 + 0) * 512 + dbase;
  const float* w1 = Wd + (e0 + 1) * 512 + dbase;
  const float* xr = hx + lane * 512 + dbase;
  float a0=0, a1=0;
  #pragma unroll 8
  for (int d = 0; d < 128; d += 4) {
    float4 xv = *(const float4*)(xr + d);
    float4 v0 = *(const float4*)(w0 + d);
    float4 v1 = *(const float4*)(w1 + d);
    FMA4(a0, xv, v0); FMA4(a1, xv, v1);
  }
  part_s[wu][lane][0]=a0; part_s[wu][lane][1]=a1;
  __syncthreads();
  if (t < 64) {
    float2 r;
    r.x = part_s[0][t][0]+part_s[1][t][0]+part_s[2][t][0]+part_s[3][t][0] + bd[e0+0];
    r.y = part_s[0][t][1]+part_s[1][t][1]+part_s[2][t][1]+part_s[3][t][1] + bd[e0+1];
    *(float2*)(q + t * 512 + e0) = r;
  }
}

// ---------------- scores[b,n] = Swr - 2*sum_e wr[e]*rcp(exp2(C2*(q+enc))+1) + br
// 1024 blocks (4/CU): b = bid>>4, 32-n chunk = bid&15. 16 lanes split e, 4 n/wave.
// Epilogue: per-row packed atomicMax (LDS-combined, 1 global atomic/block).
__global__ __launch_bounds__(256) void kscore(const float* __restrict__ enc,
                                              const float* __restrict__ q,
                                              const float* __restrict__ wr,
                                              const float* __restrict__ br,
                                              float* __restrict__ scores,
                                              unsigned long long* __restrict__ mtop) {
  __shared__ unsigned long long lmax;
  const int bid = blockIdx.x;
  const int b = bid >> 4, c = bid & 15;
  const int t = threadIdx.x, lane = t & 63, wu = t >> 6;
  const int le = lane & 15, nl = lane >> 4;
  if (t == 0) lmax = 0ULL;
  const float C2 = 2.8853900817779268f;   // 2*log2(e)
  float4 wv[8], cq[8];
  const float* qrow = q + b * 512 + le * 4;
  const float* wrp  = wr + le * 4;
  float swv = 0.0f;
  #pragma unroll
  for (int j = 0; j < 8; ++j) {
    wv[j] = *(const float4*)(wrp + 64 * j);
    swv += wv[j].x + wv[j].y + wv[j].z + wv[j].w;
    float4 qv = *(const float4*)(qrow + 64 * j);
    cq[j].x = C2*qv.x; cq[j].y = C2*qv.y; cq[j].z = C2*qv.z; cq[j].w = C2*qv.w;
  }
  swv += __shfl_xor(swv, 1); swv += __shfl_xor(swv, 2);
  swv += __shfl_xor(swv, 4); swv += __shfl_xor(swv, 8);
  const float brv = br[0];
  __syncthreads();
  #pragma unroll
  for (int i = 0; i < 2; ++i) {
    const int n = c * 32 + wu * 8 + i * 4 + nl;
    const float* erow = enc + (b * 512 + n) * 512 + le * 4;
    float acc = 0.0f;
    #pragma unroll
    for (int j = 0; j < 8; ++j) {
      float4 ev = *(const float4*)(erow + 64 * j);
      acc = fmaf(wv[j].x, __fdividef(1.0f, __builtin_exp2f(fmaf(C2, ev.x, cq[j].x)) + 1.0f), acc);
      acc = fmaf(wv[j].y, __fdividef(1.0f, __builtin_exp2f(fmaf(C2, ev.y, cq[j].y)) + 1.0f), acc);
      acc = fmaf(wv[j].z, __fdividef(1.0f, __builtin_exp2f(fmaf(C2, ev.z, cq[j].z)) + 1.0f), acc);
      acc = fmaf(wv[j].w, __fdividef(1.0f, __builtin_exp2f(fmaf(C2, ev.w, cq[j].w)) + 1.0f), acc);
    }
    acc += __shfl_xor(acc, 1); acc += __shfl_xor(acc, 2);
    acc += __shfl_xor(acc, 4); acc += __shfl_xor(acc, 8);
    if (le == 0) {
      const float sc = swv - 2.0f * acc + brv;
      scores[b * 512 + n] = sc;
      atomicMax(&lmax, pack_score(sc, n));
    }
  }
  __syncthreads();
  if (t == 0) atomicMax(&mtop[b], lmax);
}

// ---------------- final-step softmax/argmax (writes t=63 outputs)
__global__ __launch_bounds__(256) void kfin(const float* __restrict__ scores,
                                            const unsigned long long* __restrict__ mtop,
                                            float* __restrict__ out_logp,
                                            float* __restrict__ out_idx) {
  __shared__ float sw[4];
  const int b = blockIdx.x, t = threadIdx.x, lane = t & 63, w = t >> 6;
  const float* srow = scores + b * 512;
  const float s1 = srow[t], s2 = srow[t + 256];
  const unsigned long long p = mtop[b];
  const float mx = unpack_score(p);
  float ssum = __expf(s1 - mx) + __expf(s2 - mx);
  #pragma unroll
  for (int m = 1; m <= 32; m <<= 1) ssum += __shfl_xor(ssum, m);
  if (lane == 0) sw[w] = ssum;
  __syncthreads();
  const float lse = mx + __logf(sw[0] + sw[1] + sw[2] + sw[3]);
  float* orow = out_logp + (b * 64 + 63) * 512;
  orow[t]       = s1 - lse;
  orow[t + 256] = s2 - lse;
  if (t == 0) out_idx[b * 64 + 63] = (float)unpack_idx(p);
}

extern "C" void kernel_launch(void* const* d_in, const int* in_sizes, int n_in,
                              void* d_out, int out_size, void* d_ws, size_t ws_size,
                              hipStream_t stream) {
  const float* TE   = (const float*)d_in[0];   // [64,512,1024]
  const float* encd = (const float*)d_in[1];   // [64,1024]
  const float* W_ih = (const float*)d_in[2];   // [2048,1024]
  const float* b_ih = (const float*)d_in[3];   // [2048]
  const float* b_hh = (const float*)d_in[4];   // [2048]
  const float* Wd   = (const float*)d_in[5];   // [512,512]
  const float* bd   = (const float*)d_in[6];   // [512]
  const float* We   = (const float*)d_in[7];   // [512,1024]
  const float* be   = (const float*)d_in[8];   // [512]
  const float* wr   = (const float*)d_in[9];   // [512]
  const float* br   = (const float*)d_in[10];  // [1]

  float* out     = (float*)d_out;              // logp [64][64][512]
  float* out_idx = out + 64 * 64 * 512;        // indices as float [64][64]

  float* enc    = (float*)d_ws;                // 16,777,216 f (64 MB)
  float* scores = enc + 16777216;              // 32,768 f
  float* hx     = scores + 32768;              // 32,768 f
  float* q      = hx + 32768;                  // 32,768 f
  unsigned long long* mbuf0 = (unsigned long long*)(q + 32768);  // 64 u64
  unsigned long long* mbuf1 = mbuf0 + 64;                        // 64 u64

  kenc<<<dim3(256, 4), 256, 0, stream>>>(TE, We, be, enc);
  for (int t = 0; t < 64; ++t) {
    unsigned long long* mprev = (t & 1) ? mbuf0 : mbuf1;  // written by kscore(t-1)
    unsigned long long* mcur  = (t & 1) ? mbuf1 : mbuf0;  // written by kscore(t)
    kstep<<<256, 256, 0, stream>>>(TE, encd, W_ih, b_ih, b_hh, scores, mprev,
                                   mcur, hx, out, out_idx, t);
    kq<<<256, 256, 0, stream>>>(hx, Wd, bd, q);
    kscore<<<1024, 256, 0, stream>>>(enc, q, wr, br, scores, mcur);
  }
  kfin<<<64, 256, 0, stream>>>(scores, mbuf1, out, out_idx);
}